// Round 7
// baseline (10456.660 us; speedup 1.0000x reference)
//
#include <hip/hip_runtime.h>

#define B_ 64
#define T_ 4096
#define D_ 128
#define H_ 256

// Barrier that waits only on LDS ops (lgkmcnt), NOT on in-flight global
// loads/stores (vmcnt). __syncthreads() would drain vmcnt(0) every step,
// serializing the xp prefetch (HBM ~900 cyc) and h store retire into the
// critical path. Our per-step cross-thread hazards are LDS-only.
__device__ __forceinline__ void barrier_lgkm() {
    asm volatile("s_waitcnt lgkmcnt(0)" ::: "memory");
    __builtin_amdgcn_s_barrier();
    asm volatile("" ::: "memory");
}

// ---------------------------------------------------------------------------
// Kernel A: xp = x @ Wx + bx, written into `out`. (unchanged this round)
// ---------------------------------------------------------------------------
__global__ __launch_bounds__(1024) void xp_kernel(const float* __restrict__ x,
                                                  const float* __restrict__ Wx,
                                                  const float* __restrict__ bx,
                                                  float* __restrict__ out) {
    __shared__ float xs[64 * D_];
    const int tid = threadIdx.x;
    const int j = tid & 255;
    const int q = tid >> 8;                    // 0..3 -> rows 16q..16q+15
    const long row0 = (long)blockIdx.x * 64;

    const float4* xg = (const float4*)(x + row0 * D_);
    float4* xs4 = (float4*)xs;
    for (int i = tid; i < (64 * D_) / 4; i += 1024) xs4[i] = xg[i];
    __syncthreads();

    float acc[16];
#pragma unroll
    for (int r = 0; r < 16; ++r) acc[r] = 0.f;

    for (int k0 = 0; k0 < D_; k0 += 4) {
        const float w0 = Wx[(k0 + 0) * H_ + j];
        const float w1 = Wx[(k0 + 1) * H_ + j];
        const float w2 = Wx[(k0 + 2) * H_ + j];
        const float w3 = Wx[(k0 + 3) * H_ + j];
#pragma unroll
        for (int r = 0; r < 16; ++r) {
            const float4 xv = *(const float4*)(&xs[(q * 16 + r) * D_ + k0]);  // broadcast
            acc[r] += xv.x * w0 + xv.y * w1 + xv.z * w2 + xv.w * w3;
        }
    }

    const float bj = bx[j];
#pragma unroll
    for (int r = 0; r < 16; ++r) {
        out[(row0 + q * 16 + r) * H_ + j] = acc[r] + bj;   // coalesced across j
    }
}

// ---------------------------------------------------------------------------
// Kernel B: per-batch recurrence h_t = tanh(xp_t + h_{t-1} @ Wh + bh).
// grid = 64 blocks, 256 threads (4 waves, 1/SIMD).
//
// Minimum-latency-chain structure (evidence: rounds 1/5 showed step time
// invariant to LDS/VALU instruction count -> chain-bound, and round 6's
// lane-pair k-split put 2 same-bank rows per ds_read -> 2.7e8 conflicts).
// Each lane owns ONE output j and holds the FULL Wh column (256 floats,
// wreg[64] float4 = 256 VGPRs; no spill below 512 per m08). Per step:
//   barrier -> 64 same-address broadcast ds_read_b128 of h (zero conflicts
//   by construction) -> 256 FMAs into 8 accumulators (chains of 32) ->
//   tanh -> hs write + coalesced store. NO k-reduction of any kind
//   (no shuffle, no partial LDS round-trip), no divergent epilogue.
// hs double-buffered; ONE lgkm barrier/step closes RAW (writes drain
// pre-barrier) and WAR (reads drain pre-barrier, overwrite post-barrier).
// xp t+2 prefetch and h stores stay vmcnt-in-flight across barriers.
// ---------------------------------------------------------------------------
__global__ __launch_bounds__(256, 1) void rnn_kernel(const float* __restrict__ Wh,
                                                     const float* __restrict__ bh,
                                                     float* __restrict__ out) {
    const int b = blockIdx.x;
    const int j = threadIdx.x;                 // output index 0..255

    __shared__ float hs[2][H_];

    // wreg[c] = Wh[4c..4c+3][j] — full column in registers (coalesced loads)
    float4 wreg[64];
#pragma unroll
    for (int c = 0; c < 64; ++c) {
        wreg[c].x = Wh[(4 * c + 0) * H_ + j];
        wreg[c].y = Wh[(4 * c + 1) * H_ + j];
        wreg[c].z = Wh[(4 * c + 2) * H_ + j];
        wreg[c].w = Wh[(4 * c + 3) * H_ + j];
    }
    const float bhj = bh[j];

    hs[0][j] = 0.f;
    hs[1][j] = 0.f;
    __syncthreads();                           // once; vmcnt drain here is fine

    float* obase = out + (long)b * T_ * H_;
    float xp0 = obase[j];                      // xp[b][0][j]
    float xp1 = obase[H_ + j];                 // xp[b][1][j]

#pragma unroll 2
    for (int t = 0; t < T_; ++t) {
        const float* hb = hs[t & 1];

        // prefetch xp for t+2; vmcnt wait lands ~1 full step later
        float xp2 = 0.f;
        if (t + 2 < T_) xp2 = obase[(long)(t + 2) * H_ + j];

        // 64 broadcast b128 reads + 256 FMAs, 8 accumulators (32-FMA chains)
        float a0 = 0.f, a1 = 0.f, a2 = 0.f, a3 = 0.f;
        float a4 = 0.f, a5 = 0.f, a6 = 0.f, a7 = 0.f;
#pragma unroll
        for (int c = 0; c < 64; c += 2) {
            const float4 h0 = *(const float4*)(&hb[4 * c]);        // broadcast
            const float4 h1 = *(const float4*)(&hb[4 * c + 4]);    // broadcast
            a0 += h0.x * wreg[c].x;
            a1 += h0.y * wreg[c].y;
            a2 += h0.z * wreg[c].z;
            a3 += h0.w * wreg[c].w;
            a4 += h1.x * wreg[c + 1].x;
            a5 += h1.y * wreg[c + 1].y;
            a6 += h1.z * wreg[c + 1].z;
            a7 += h1.w * wreg[c + 1].w;
        }
        float sum = (((a0 + a1) + (a2 + a3)) + ((a4 + a5) + (a6 + a7)))
                    + (xp0 + bhj);
        // branchless tanh: clamp, e = exp(2s), (e-1)/(e+1)
        sum = fminf(15.f, fmaxf(-15.f, sum));
        const float e = __expf(2.f * sum);
        const float hn = __fdividef(e - 1.f, e + 1.f);
        hs[(t + 1) & 1][j] = hn;
        obase[(long)t * H_ + j] = hn;          // fire-and-forget store
        xp0 = xp1;
        xp1 = xp2;

        barrier_lgkm();                        // the ONLY per-step barrier
    }
}

extern "C" void kernel_launch(void* const* d_in, const int* in_sizes, int n_in,
                              void* d_out, int out_size, void* d_ws, size_t ws_size,
                              hipStream_t stream) {
    const float* x  = (const float*)d_in[0];
    const float* Wx = (const float*)d_in[1];
    const float* bx = (const float*)d_in[2];
    const float* Wh = (const float*)d_in[3];
    const float* bh = (const float*)d_in[4];
    float* out = (float*)d_out;

    xp_kernel<<<(B_ * T_) / 64, 1024, 0, stream>>>(x, Wx, bx, out);
    rnn_kernel<<<B_, 256, 0, stream>>>(Wh, bh, out);
}

// Round 9
// 3423.451 us; speedup vs baseline: 3.0544x; 3.0544x over previous
//
#include <hip/hip_runtime.h>

#define B_ 64
#define T_ 4096
#define D_ 128
#define H_ 256

// Barrier that waits only on LDS ops (lgkmcnt), NOT on in-flight global
// loads/stores (vmcnt). __syncthreads() would drain vmcnt(0) every step,
// serializing the xp prefetch (HBM ~900 cyc) and h store retire into the
// critical path. Our per-step cross-thread hazards are LDS-only.
__device__ __forceinline__ void barrier_lgkm() {
    asm volatile("s_waitcnt lgkmcnt(0)" ::: "memory");
    __builtin_amdgcn_s_barrier();
    asm volatile("" ::: "memory");
}

// Pin a float into a VGPR: opaque asm "modifies" it, so the compiler must
// materialize the loaded value into a register before the t-loop and CANNOT
// rematerialize it by re-loading from global inside the loop. (Session
// evidence: VGPR_Count=48 with a 64-float weight array -> the compiler was
// sinking the Wh loads into the loop, re-streaming ~200KB/step from L2.)
#define PIN(x) asm volatile("" : "+v"(x))

// ---------------------------------------------------------------------------
// Kernel A: xp = x @ Wx + bx, written into `out`. (unchanged this round)
// ---------------------------------------------------------------------------
__global__ __launch_bounds__(1024) void xp_kernel(const float* __restrict__ x,
                                                  const float* __restrict__ Wx,
                                                  const float* __restrict__ bx,
                                                  float* __restrict__ out) {
    __shared__ float xs[64 * D_];
    const int tid = threadIdx.x;
    const int j = tid & 255;
    const int q = tid >> 8;                    // 0..3 -> rows 16q..16q+15
    const long row0 = (long)blockIdx.x * 64;

    const float4* xg = (const float4*)(x + row0 * D_);
    float4* xs4 = (float4*)xs;
    for (int i = tid; i < (64 * D_) / 4; i += 1024) xs4[i] = xg[i];
    __syncthreads();

    float acc[16];
#pragma unroll
    for (int r = 0; r < 16; ++r) acc[r] = 0.f;

    for (int k0 = 0; k0 < D_; k0 += 4) {
        const float w0 = Wx[(k0 + 0) * H_ + j];
        const float w1 = Wx[(k0 + 1) * H_ + j];
        const float w2 = Wx[(k0 + 2) * H_ + j];
        const float w3 = Wx[(k0 + 3) * H_ + j];
#pragma unroll
        for (int r = 0; r < 16; ++r) {
            const float4 xv = *(const float4*)(&xs[(q * 16 + r) * D_ + k0]);  // broadcast
            acc[r] += xv.x * w0 + xv.y * w1 + xv.z * w2 + xv.w * w3;
        }
    }

    const float bj = bx[j];
#pragma unroll
    for (int r = 0; r < 16; ++r) {
        out[(row0 + q * 16 + r) * H_ + j] = acc[r] + bj;   // coalesced across j
    }
}

// ---------------------------------------------------------------------------
// Kernel B: per-batch recurrence h_t = tanh(xp_t + h_{t-1} @ Wh + bh).
// grid = 64 blocks, 1024 threads (16 waves) — the R5 structure (best
// measured: 3020 µs) + PINNED weight registers.
//
// Wave s owns k-slice [16s,16s+16); lane l computes outputs j=4l..4l+3.
// Each thread holds Wh[16s..16s+15][4l..4l+3] = 16 float4, PINNED into
// VGPRs (64 + ~40 live ≈ 104 < 128-VGPR budget from launch_bounds(1024,4)
// = 4 waves/EU = 16 waves = 1 block/CU, same occupancy as R5).
// Per step: 4 broadcast ds_read_b128 of h slice -> 64 FMAs -> b128 partial
// write -> lgkm barrier -> waves 0..3 reduce 64 outputs (16 stride-1 b32 =
// 2-way alias, free) + xp + bias + fast tanh -> hs write + coalesced
// store -> lgkm barrier. xp t+2 prefetch and h stores stay vmcnt-in-flight.
// ---------------------------------------------------------------------------
__global__ __launch_bounds__(1024, 4) void rnn_kernel(const float* __restrict__ Wh,
                                                      const float* __restrict__ bh,
                                                      float* __restrict__ out) {
    const int b = blockIdx.x;
    const int tid = threadIdx.x;
    const int lane = tid & 63;
    const int s = tid >> 6;                    // wave id 0..15 = k-slice
    const int j0 = lane << 2;                  // phase-1 outputs j0..j0+3
    const int jr = ((s & 3) << 6) + lane;      // phase-2 output (waves 0..3)

    __shared__ float hs[H_];
    __shared__ float partial[16][H_];

    // wreg[kk] = Wh[16s+kk][j0..j0+3]  (coalesced b128 loads, 64 VGPRs)
    float4 wreg[16];
#pragma unroll
    for (int kk = 0; kk < 16; ++kk)
        wreg[kk] = *(const float4*)(&Wh[(s * 16 + kk) * H_ + j0]);
    // Force residency: without this the compiler sinks these loads into the
    // t-loop and re-streams ~200KB/step/CU of Wh from L2 (the 1770-cyc floor).
#pragma unroll
    for (int kk = 0; kk < 16; ++kk) {
        PIN(wreg[kk].x); PIN(wreg[kk].y); PIN(wreg[kk].z); PIN(wreg[kk].w);
    }

    const float bhj = bh[jr];

    if (tid < H_) hs[tid] = 0.f;
    __syncthreads();                           // once; vmcnt drain here is fine

    float* obase = out + (long)b * T_ * H_;
    float xp0 = 0.f, xp1 = 0.f;
    if (s < 4) {
        xp0 = obase[jr];                       // xp[b][0][jr]
        xp1 = obase[H_ + jr];                  // xp[b][1][jr]
    }

#pragma unroll 2
    for (int t = 0; t < T_; ++t) {
        // prefetch xp for t+2; vmcnt wait lands ~1 full step later
        float xp2 = 0.f;
        if (s < 4 && t + 2 < T_) xp2 = obase[(long)(t + 2) * H_ + jr];

        // phase 1: 4 broadcast b128 reads + 64 FMAs into 4 accumulators
        float4 acc;
        acc.x = 0.f; acc.y = 0.f; acc.z = 0.f; acc.w = 0.f;
#define FMA4(HE, W) { const float he_ = (HE); const float4 w_ = (W); \
        acc.x += he_ * w_.x; acc.y += he_ * w_.y;                     \
        acc.z += he_ * w_.z; acc.w += he_ * w_.w; }
#pragma unroll
        for (int c = 0; c < 4; ++c) {
            const float4 hv = *(const float4*)(&hs[s * 16 + c * 4]);  // broadcast
            FMA4(hv.x, wreg[c * 4 + 0])
            FMA4(hv.y, wreg[c * 4 + 1])
            FMA4(hv.z, wreg[c * 4 + 2])
            FMA4(hv.w, wreg[c * 4 + 3])
        }
#undef FMA4
        *(float4*)(&partial[s][j0]) = acc;     // conflict-free b128 write
        barrier_lgkm();

        // phase 2: waves 0..3 reduce 64 outputs each (1 per thread)
        if (s < 4) {
            float v[16];
#pragma unroll
            for (int s2 = 0; s2 < 16; ++s2) v[s2] = partial[s2][jr];
            const float t0 = (v[0] + v[1]) + (v[2] + v[3]);
            const float t1 = (v[4] + v[5]) + (v[6] + v[7]);
            const float t2 = (v[8] + v[9]) + (v[10] + v[11]);
            const float t3 = (v[12] + v[13]) + (v[14] + v[15]);
            float sum = ((t0 + t1) + (t2 + t3)) + (xp0 + bhj);
            // branchless tanh: clamp, e = exp(2s), (e-1)/(e+1)
            sum = fminf(15.f, fmaxf(-15.f, sum));
            const float e = __expf(2.f * sum);
            const float hn = __fdividef(e - 1.f, e + 1.f);
            hs[jr] = hn;
            obase[(long)t * H_ + jr] = hn;     // fire-and-forget store
            xp0 = xp1;
            xp1 = xp2;
        }
        barrier_lgkm();
    }
}

extern "C" void kernel_launch(void* const* d_in, const int* in_sizes, int n_in,
                              void* d_out, int out_size, void* d_ws, size_t ws_size,
                              hipStream_t stream) {
    const float* x  = (const float*)d_in[0];
    const float* Wx = (const float*)d_in[1];
    const float* bx = (const float*)d_in[2];
    const float* Wh = (const float*)d_in[3];
    const float* bh = (const float*)d_in[4];
    float* out = (float*)d_out;

    xp_kernel<<<(B_ * T_) / 64, 1024, 0, stream>>>(x, Wx, bx, out);
    rnn_kernel<<<B_, 1024, 0, stream>>>(Wh, bh, out);
}

// Round 11
// 3135.411 us; speedup vs baseline: 3.3350x; 1.0919x over previous
//
#include <hip/hip_runtime.h>

#define B_ 64
#define T_ 4096
#define D_ 128
#define H_ 256

// Barrier that waits only on LDS ops (lgkmcnt), NOT on in-flight global
// loads/stores (vmcnt). __syncthreads() would drain vmcnt(0) every step,
// serializing the xp prefetch (HBM ~900 cyc) and h store retire into the
// critical path. Our per-step cross-thread hazards are LDS-only.
__device__ __forceinline__ void barrier_lgkm() {
    asm volatile("s_waitcnt lgkmcnt(0)" ::: "memory");
    __builtin_amdgcn_s_barrier();
    asm volatile("" ::: "memory");
}

// Opaque register pin: the asm output cannot be rematerialized by re-loading
// from memory (even though Wh is const __restrict__), so the value must stay
// in a VGPR (or spill -> visible as VGPR_Count jump). Applied to NAMED
// scalars only: indexed arrays (wreg[16]) were never SROA-promoted and lived
// in scratch, which is why R9's PIN left VGPR_Count at 48.
#define PIN(x) asm volatile("" : "+v"(x))
#define PIN4(v) { PIN(v.x); PIN(v.y); PIN(v.z); PIN(v.w); }

// ---------------------------------------------------------------------------
// Kernel A: xp = x @ Wx + bx, written into `out`. (unchanged this round)
// ---------------------------------------------------------------------------
__global__ __launch_bounds__(1024) void xp_kernel(const float* __restrict__ x,
                                                  const float* __restrict__ Wx,
                                                  const float* __restrict__ bx,
                                                  float* __restrict__ out) {
    __shared__ float xs[64 * D_];
    const int tid = threadIdx.x;
    const int j = tid & 255;
    const int q = tid >> 8;                    // 0..3 -> rows 16q..16q+15
    const long row0 = (long)blockIdx.x * 64;

    const float4* xg = (const float4*)(x + row0 * D_);
    float4* xs4 = (float4*)xs;
    for (int i = tid; i < (64 * D_) / 4; i += 1024) xs4[i] = xg[i];
    __syncthreads();

    float acc[16];
#pragma unroll
    for (int r = 0; r < 16; ++r) acc[r] = 0.f;

    for (int k0 = 0; k0 < D_; k0 += 4) {
        const float w0 = Wx[(k0 + 0) * H_ + j];
        const float w1 = Wx[(k0 + 1) * H_ + j];
        const float w2 = Wx[(k0 + 2) * H_ + j];
        const float w3 = Wx[(k0 + 3) * H_ + j];
#pragma unroll
        for (int r = 0; r < 16; ++r) {
            const float4 xv = *(const float4*)(&xs[(q * 16 + r) * D_ + k0]);  // broadcast
            acc[r] += xv.x * w0 + xv.y * w1 + xv.z * w2 + xv.w * w3;
        }
    }

    const float bj = bx[j];
#pragma unroll
    for (int r = 0; r < 16; ++r) {
        out[(row0 + q * 16 + r) * H_ + j] = acc[r] + bj;   // coalesced across j
    }
}

// ---------------------------------------------------------------------------
// Kernel B: per-batch recurrence h_t = tanh(xp_t + h_{t-1} @ Wh + bh).
// grid = 64 blocks, 1024 threads (16 waves) — R5/R9 structure, but the
// 16 weight float4s are NAMED variables (w00..w15, guaranteed SSA) + PIN'd.
// Session evidence: as an array they lived in scratch (VGPR_Count=48 with
// 64 floats notionally live) and Wh was re-streamed ~256KB/step/CU from
// scratch/L2 — the ~1700-cyc step floor that made R5/R6 edits null.
//
// Wave s owns k-slice [16s,16s+16); lane l computes outputs j=4l..4l+3.
// Per step: 4 broadcast ds_read_b128 of h slice -> 64 FMAs -> b128 partial
// write -> lgkm barrier -> waves 0..3 reduce 64 outputs (16 stride-1 b32 =
// 2-way alias, free; named scalars, no array) + xp + bias + fast tanh ->
// hs write + coalesced store -> lgkm barrier. xp t+2 prefetch and h stores
// stay vmcnt-in-flight across barriers.
// ---------------------------------------------------------------------------
__global__ __launch_bounds__(1024, 4) void rnn_kernel(const float* __restrict__ Wh,
                                                      const float* __restrict__ bh,
                                                      float* __restrict__ out) {
    const int b = blockIdx.x;
    const int tid = threadIdx.x;
    const int lane = tid & 63;
    const int s = tid >> 6;                    // wave id 0..15 = k-slice
    const int j0 = lane << 2;                  // phase-1 outputs j0..j0+3
    const int jr = ((s & 3) << 6) + lane;      // phase-2 output (waves 0..3)

    __shared__ float hs[H_];
    __shared__ float partial[16][H_];

    // Named weight registers: w<kk> = Wh[16s+kk][j0..j0+3] (coalesced b128)
#define LDW(kk) (*(const float4*)(&Wh[(s * 16 + (kk)) * H_ + j0]))
    float4 w00 = LDW(0),  w01 = LDW(1),  w02 = LDW(2),  w03 = LDW(3);
    float4 w04 = LDW(4),  w05 = LDW(5),  w06 = LDW(6),  w07 = LDW(7);
    float4 w08 = LDW(8),  w09 = LDW(9),  w10 = LDW(10), w11 = LDW(11);
    float4 w12 = LDW(12), w13 = LDW(13), w14 = LDW(14), w15 = LDW(15);
#undef LDW
    PIN4(w00); PIN4(w01); PIN4(w02); PIN4(w03);
    PIN4(w04); PIN4(w05); PIN4(w06); PIN4(w07);
    PIN4(w08); PIN4(w09); PIN4(w10); PIN4(w11);
    PIN4(w12); PIN4(w13); PIN4(w14); PIN4(w15);

    const float bhj = bh[jr];

    if (tid < H_) hs[tid] = 0.f;
    __syncthreads();                           // once; vmcnt drain here is fine

    float* obase = out + (long)b * T_ * H_;
    float xp0 = 0.f, xp1 = 0.f;
    if (s < 4) {
        xp0 = obase[jr];                       // xp[b][0][jr]
        xp1 = obase[H_ + jr];                  // xp[b][1][jr]
    }

#pragma unroll 2
    for (int t = 0; t < T_; ++t) {
        // prefetch xp for t+2; vmcnt wait lands ~1 full step later
        float xp2 = 0.f;
        if (s < 4 && t + 2 < T_) xp2 = obase[(long)(t + 2) * H_ + jr];

        // phase 1: 4 broadcast b128 reads + 64 FMAs into 4 accumulators
        const float4 h0 = *(const float4*)(&hs[s * 16 + 0]);   // broadcast
        const float4 h1 = *(const float4*)(&hs[s * 16 + 4]);   // broadcast
        const float4 h2 = *(const float4*)(&hs[s * 16 + 8]);   // broadcast
        const float4 h3 = *(const float4*)(&hs[s * 16 + 12]);  // broadcast
        float4 acc; acc.x = 0.f; acc.y = 0.f; acc.z = 0.f; acc.w = 0.f;
#define FMA4(HE, W) { const float he_ = (HE);                       \
        acc.x += he_ * W.x; acc.y += he_ * W.y;                     \
        acc.z += he_ * W.z; acc.w += he_ * W.w; }
        FMA4(h0.x, w00) FMA4(h0.y, w01) FMA4(h0.z, w02) FMA4(h0.w, w03)
        FMA4(h1.x, w04) FMA4(h1.y, w05) FMA4(h1.z, w06) FMA4(h1.w, w07)
        FMA4(h2.x, w08) FMA4(h2.y, w09) FMA4(h2.z, w10) FMA4(h2.w, w11)
        FMA4(h3.x, w12) FMA4(h3.y, w13) FMA4(h3.z, w14) FMA4(h3.w, w15)
#undef FMA4
        *(float4*)(&partial[s][j0]) = acc;     // conflict-free b128 write
        barrier_lgkm();

        // phase 2: waves 0..3 reduce 64 outputs each (named scalars, no array)
        if (s < 4) {
            const float* pc = &partial[0][jr];
            const float p0  = pc[0 * H_],  p1  = pc[1 * H_];
            const float p2  = pc[2 * H_],  p3  = pc[3 * H_];
            const float p4  = pc[4 * H_],  p5  = pc[5 * H_];
            const float p6  = pc[6 * H_],  p7  = pc[7 * H_];
            const float p8  = pc[8 * H_],  p9  = pc[9 * H_];
            const float p10 = pc[10 * H_], p11 = pc[11 * H_];
            const float p12 = pc[12 * H_], p13 = pc[13 * H_];
            const float p14 = pc[14 * H_], p15 = pc[15 * H_];
            const float t0 = (p0 + p1) + (p2 + p3);
            const float t1 = (p4 + p5) + (p6 + p7);
            const float t2 = (p8 + p9) + (p10 + p11);
            const float t3 = (p12 + p13) + (p14 + p15);
            float sum = ((t0 + t1) + (t2 + t3)) + (xp0 + bhj);
            // branchless tanh: clamp, e = exp(2s), (e-1)/(e+1)
            sum = fminf(15.f, fmaxf(-15.f, sum));
            const float e = __expf(2.f * sum);
            const float hn = __fdividef(e - 1.f, e + 1.f);
            hs[jr] = hn;
            obase[(long)t * H_ + jr] = hn;     // fire-and-forget store
            xp0 = xp1;
            xp1 = xp2;
        }
        barrier_lgkm();
    }
}

extern "C" void kernel_launch(void* const* d_in, const int* in_sizes, int n_in,
                              void* d_out, int out_size, void* d_ws, size_t ws_size,
                              hipStream_t stream) {
    const float* x  = (const float*)d_in[0];
    const float* Wx = (const float*)d_in[1];
    const float* bx = (const float*)d_in[2];
    const float* Wh = (const float*)d_in[3];
    const float* bh = (const float*)d_in[4];
    float* out = (float*)d_out;

    xp_kernel<<<(B_ * T_) / 64, 1024, 0, stream>>>(x, Wx, bx, out);
    rnn_kernel<<<B_, 1024, 0, stream>>>(Wh, bh, out);
}